// Round 2
// baseline (1308.762 us; speedup 1.0000x reference)
//
#include <hip/hip_runtime.h>

// ============================================================================
// R1 (resubmit): full bf16-MFMA pipeline.
//  LN1 -> (commuted) fusion GEMMs (K=256,N=768) -> resample+sum -> QKV GEMMs
//  -> window-MHA (3 MFMAs per (window,head)) -> proj GEMM (+residual, f32 out)
//  -> LN2 -> FFN GEMM (accumulate into d_out).
// Precision: bf16 operands, f32 accumulate; residual path exact f32.
// Workspace: ~443 MB, regions reused (xn->attn, Q->qkv, s->ln2).
// ============================================================================

typedef unsigned short ushort_t;      // bf16 bits
typedef unsigned int   uint32;
typedef __attribute__((ext_vector_type(8))) short short8;   // 8 x bf16 (4 VGPR)
typedef __attribute__((ext_vector_type(4))) float f32x4;

#define GLOBAL_AS __attribute__((address_space(1)))
#define LDS_AS    __attribute__((address_space(3)))

__device__ __forceinline__ float b2f(ushort_t h) {
    union { uint32 u; float f; } x; x.u = ((uint32)h) << 16; return x.f;
}
__device__ __forceinline__ ushort_t f2b(float f) {
    union { float f; uint32 u; } x; x.f = f;
    uint32 u = x.u;
    return (ushort_t)((u + 0x7FFFu + ((u >> 16) & 1u)) >> 16);   // RNE
}
__device__ __forceinline__ void async_ld16(const void* g, void* l) {
    __builtin_amdgcn_global_load_lds((const GLOBAL_AS uint32*)g, (LDS_AS uint32*)l, 16, 0, 0);
}

// ---------------------------------------------------------------------------
// LayerNorm: one wave per token (C=256). SPLIT=true scatters into per-scale
// contiguous buffers; false writes a single contiguous buffer.
// ---------------------------------------------------------------------------
template<bool SPLIT>
__global__ __launch_bounds__(256)
void ln_kernel(const float* __restrict__ x, const float* __restrict__ g,
               const float* __restrict__ bb,
               ushort_t* d0, ushort_t* d1, ushort_t* d2, int ntok)
{
    int wid  = blockIdx.x * 4 + (threadIdx.x >> 6);
    int lane = threadIdx.x & 63;
    if (wid >= ntok) return;
    const float* row = x + (size_t)wid * 256;
    float4 v = *(const float4*)(row + lane * 4);
    float s  = v.x + v.y + v.z + v.w;
    float s2 = v.x*v.x + v.y*v.y + v.z*v.z + v.w*v.w;
#pragma unroll
    for (int mask = 1; mask < 64; mask <<= 1) {
        s  += __shfl_xor(s,  mask);
        s2 += __shfl_xor(s2, mask);
    }
    float mean = s * (1.f/256.f);
    float var  = s2 * (1.f/256.f) - mean*mean;
    float rstd = rsqrtf(var + 1e-5f);
    ushort_t* dst;
    if (SPLIT) {
        int b = wid / 5376, n = wid % 5376;
        if      (n < 4096) dst = d0 + ((size_t)b*4096 + n)        * 256;
        else if (n < 5120) dst = d1 + ((size_t)b*1024 + (n-4096)) * 256;
        else               dst = d2 + ((size_t)b*256  + (n-5120)) * 256;
    } else {
        dst = d0 + (size_t)wid * 256;
    }
    int c = lane * 4;
    float4 gg = *(const float4*)(g  + c);
    float4 bv = *(const float4*)(bb + c);
    ushort4 o;
    o.x = f2b((v.x-mean)*rstd*gg.x + bv.x);
    o.y = f2b((v.y-mean)*rstd*gg.y + bv.y);
    o.z = f2b((v.z-mean)*rstd*gg.z + bv.z);
    o.w = f2b((v.w-mean)*rstd*gg.w + bv.w);
    *(ushort4*)(dst + c) = o;
}

// ---------------------------------------------------------------------------
// Weight repack/cast to bf16.
// Wf[j][o][c] (3x768x256): fused-conv weight, o<256->conv1, <512->conv2, else conv3,
//   source slice conv_w[o&255][j*256+c].  Wq: 3x(768x256) qkv casts.
//   Wp: 3x(256x256) proj casts. Wff: 256x256 ffn cast.
// ---------------------------------------------------------------------------
__global__ __launch_bounds__(256)
void repack(const float* c1, const float* c2, const float* c3,
            const float* q1, const float* q2, const float* q3,
            const float* p1, const float* p2, const float* p3,
            const float* fw,
            ushort_t* Wf, ushort_t* Wq, ushort_t* Wp, ushort_t* Wff)
{
    int idx = blockIdx.x * 256 + threadIdx.x;
    if (idx < 3*768*256) {
        int j = idx / (768*256), rem = idx % (768*256);
        int o = rem >> 8, c = rem & 255;
        const float* src = (o < 256) ? c1 : (o < 512 ? c2 : c3);
        Wf[idx] = f2b(src[(size_t)(o & 255)*768 + j*256 + c]);
        return;
    }
    int i2 = idx - 3*768*256;
    if (i2 < 3*768*256) {
        const float* src = (i2 < 196608) ? q1 : (i2 < 393216 ? q2 : q3);
        Wq[i2] = f2b(src[i2 % 196608]);
        return;
    }
    int i3 = i2 - 3*768*256;
    if (i3 < 3*65536) {
        const float* src = (i3 < 65536) ? p1 : (i3 < 131072 ? p2 : p3);
        Wp[i3] = f2b(src[i3 % 65536]);
        return;
    }
    int i4 = i3 - 3*65536;
    if (i4 < 65536) Wff[i4] = f2b(fw[i4]);
}

// ---------------------------------------------------------------------------
// GEMM: out(M,Nout) = A(M,256) @ Bw(Nout,256)^T  [+bias][+resid]
// 128x128 tile, BK=64, 4 waves (2x2), each wave 64x64 via 4x4 mfma 16x16x32.
// MODE 0: bf16 store (contiguous). MODE 1: f32 store to remapped token rows
//   (+bias+resid).  MODE 2: f32 accumulate (+bias), identity rows.
// ---------------------------------------------------------------------------
template<int MODE, bool HAS_BIAS>
__global__ __launch_bounds__(256)
void gemm_k256(const ushort_t* __restrict__ A, const ushort_t* __restrict__ Bw,
               const float* __restrict__ bias, const float* __restrict__ resid,
               void* __restrict__ outp, int M, int Nout,
               int n_per_b, int N_total, int off)
{
    __shared__ ushort_t As[128][64];
    __shared__ ushort_t Bs[128][64];
    const int K = 256;
    int lane = threadIdx.x & 63;
    int w    = threadIdx.x >> 6;
    int m0 = blockIdx.y * 128;
    int n0 = blockIdx.x * 128;
    int wm = w >> 1, wn = w & 1;

    f32x4 acc[4][4];
#pragma unroll
    for (int m = 0; m < 4; ++m)
#pragma unroll
        for (int n = 0; n < 4; ++n) acc[m][n] = f32x4{0.f,0.f,0.f,0.f};

    int sr = lane >> 3;          // row within 8-row staging chunk
    int sc = (lane & 7) * 8;     // col (elements)

    for (int k0 = 0; k0 < K; k0 += 64) {
        __syncthreads();
#pragma unroll
        for (int q = 0; q < 4; ++q) {
            int rr = (w*4 + q) * 8;
            const ushort_t* ga = A  + (size_t)(m0 + rr + sr) * K + (k0 + sc);
            const ushort_t* gb = Bw + (size_t)(n0 + rr + sr) * K + (k0 + sc);
            async_ld16(ga, &As[rr][0]);
            async_ld16(gb, &Bs[rr][0]);
        }
        __syncthreads();
        int row = lane & 15;
        int kof = 8 * (lane >> 4);
#pragma unroll
        for (int kk = 0; kk < 64; kk += 32) {
            short8 af[4], bf[4];
#pragma unroll
            for (int m = 0; m < 4; ++m)
                af[m] = *(const short8*)&As[wm*64 + m*16 + row][kk + kof];
#pragma unroll
            for (int n = 0; n < 4; ++n)
                bf[n] = *(const short8*)&Bs[wn*64 + n*16 + row][kk + kof];
#pragma unroll
            for (int m = 0; m < 4; ++m)
#pragma unroll
                for (int n = 0; n < 4; ++n)
                    acc[m][n] = __builtin_amdgcn_mfma_f32_16x16x32_bf16(
                        af[m], bf[n], acc[m][n], 0, 0, 0);
        }
    }

    int cr = (lane >> 4) * 4;
    int cc = lane & 15;
#pragma unroll
    for (int m = 0; m < 4; ++m) {
#pragma unroll
        for (int r = 0; r < 4; ++r) {
            int grow = m0 + wm*64 + m*16 + cr + r;
            size_t orow;
            if (MODE == 1) {
                int bidx = grow / n_per_b;
                int t    = grow - bidx * n_per_b;
                orow = (size_t)bidx * N_total + off + t;
            } else {
                orow = (size_t)grow;
            }
#pragma unroll
            for (int n = 0; n < 4; ++n) {
                int col = n0 + wn*64 + n*16 + cc;
                float v = acc[m][n][r];
                if (HAS_BIAS) v += bias[col];
                if (MODE == 0) {
                    ((ushort_t*)outp)[(size_t)grow * Nout + col] = f2b(v);
                } else if (MODE == 1) {
                    float* o = (float*)outp;
                    v += resid[orow * 256 + col];
                    o[orow * 256 + col] = v;
                } else {
                    float* o = (float*)outp;
                    o[orow * 256 + col] += v;
                }
            }
        }
    }
}

// ---------------------------------------------------------------------------
// Resample + sum (commuted conv).  up_taps: 2x bilinear, half-pixel centers,
// edge clamp (== jax renormalized triangle at 2x).
// ---------------------------------------------------------------------------
__device__ __forceinline__ void up_taps(int i, int S, int& j0, int& j1,
                                        float& w0, float& w1)
{
    int t = i >> 1;
    if (i & 1) { j0 = t; j1 = (t+1 < S) ? t+1 : S-1; w0 = 0.75f; w1 = 0.25f; }
    else       { j0 = (t > 0) ? t-1 : 0; j1 = t;     w0 = 0.25f; w1 = 0.75f; }
}

__global__ __launch_bounds__(256)
void fuse1(const ushort_t* __restrict__ Q1, const ushort_t* __restrict__ Q2,
           const ushort_t* __restrict__ Q3, const float* __restrict__ bias,
           ushort_t* __restrict__ s1o)
{
    int c = threadIdx.x;
    int p = blockIdx.x;                 // b*4096 + pix
    int b = p >> 12, pix = p & 4095;
    int y = pix >> 6, x = pix & 63;
    float acc = b2f(Q1[(size_t)p * 768 + c]);
    int y0,y1,x0,x1; float wy0,wy1,wx0,wx1;
    up_taps(y, 32, y0, y1, wy0, wy1);
    up_taps(x, 32, x0, x1, wx0, wx1);
    size_t q2b = (size_t)b * 1024;
    acc += wy0*wx0 * b2f(Q2[(q2b + y0*32 + x0)*768 + c]);
    acc += wy0*wx1 * b2f(Q2[(q2b + y0*32 + x1)*768 + c]);
    acc += wy1*wx0 * b2f(Q2[(q2b + y1*32 + x0)*768 + c]);
    acc += wy1*wx1 * b2f(Q2[(q2b + y1*32 + x1)*768 + c]);
    // composed double upsample from 16x16 (mid grid taps == the 32-grid taps above)
    size_t q3b = (size_t)b * 256;
#pragma unroll
    for (int ay = 0; ay < 2; ++ay) {
        int   my  = ay ? y1 : y0;
        float wmy = ay ? wy1 : wy0;
        int sy0, sy1; float wsy0, wsy1;
        up_taps(my, 16, sy0, sy1, wsy0, wsy1);
#pragma unroll
        for (int ax = 0; ax < 2; ++ax) {
            int   mx  = ax ? x1 : x0;
            float wmx = ax ? wx1 : wx0;
            int sx0, sx1; float wsx0, wsx1;
            up_taps(mx, 16, sx0, sx1, wsx0, wsx1);
            float mid = wsy0*(wsx0*b2f(Q3[(q3b + sy0*16 + sx0)*768 + c]) +
                              wsx1*b2f(Q3[(q3b + sy0*16 + sx1)*768 + c]))
                      + wsy1*(wsx0*b2f(Q3[(q3b + sy1*16 + sx0)*768 + c]) +
                              wsx1*b2f(Q3[(q3b + sy1*16 + sx1)*768 + c]));
            acc += wmy * wmx * mid;
        }
    }
    acc += bias[c];
    s1o[(size_t)p * 256 + c] = f2b(acc);
}

__global__ __launch_bounds__(256)
void fuse2(const ushort_t* __restrict__ Q1, const ushort_t* __restrict__ Q2,
           const ushort_t* __restrict__ Q3, const float* __restrict__ bias,
           ushort_t* __restrict__ s2o)
{
    int c = threadIdx.x;
    int p = blockIdx.x;                 // b*1024 + pix
    int b = p >> 10, pix = p & 1023;
    int y = pix >> 5, x = pix & 31;
    float acc = b2f(Q2[(size_t)p * 768 + 256 + c]);
    size_t q1b = (size_t)b * 4096;
    float d = 0.f;
#pragma unroll
    for (int dy = 0; dy < 2; ++dy)
#pragma unroll
        for (int dx = 0; dx < 2; ++dx)
            d += b2f(Q1[(q1b + (size_t)(2*y+dy)*64 + (2*x+dx))*768 + 256 + c]);
    acc += 0.25f * d;
    int y0,y1,x0,x1; float wy0,wy1,wx0,wx1;
    up_taps(y, 16, y0, y1, wy0, wy1);
    up_taps(x, 16, x0, x1, wx0, wx1);
    size_t q3b = (size_t)b * 256;
    acc += wy0*wx0 * b2f(Q3[(q3b + y0*16 + x0)*768 + 256 + c]);
    acc += wy0*wx1 * b2f(Q3[(q3b + y0*16 + x1)*768 + 256 + c]);
    acc += wy1*wx0 * b2f(Q3[(q3b + y1*16 + x0)*768 + 256 + c]);
    acc += wy1*wx1 * b2f(Q3[(q3b + y1*16 + x1)*768 + 256 + c]);
    acc += bias[c];
    s2o[(size_t)p * 256 + c] = f2b(acc);
}

__global__ __launch_bounds__(256)
void fuse3(const ushort_t* __restrict__ Q1, const ushort_t* __restrict__ Q2,
           const ushort_t* __restrict__ Q3, const float* __restrict__ bias,
           ushort_t* __restrict__ s3o)
{
    int c = threadIdx.x;
    int p = blockIdx.x;                 // b*256 + pix
    int b = p >> 8, pix = p & 255;
    int y = pix >> 4, x = pix & 15;
    float acc = b2f(Q3[(size_t)p * 768 + 512 + c]);
    size_t q1b = (size_t)b * 4096;
    float d = 0.f;
#pragma unroll
    for (int dy = 0; dy < 4; ++dy)
#pragma unroll
        for (int dx = 0; dx < 4; ++dx)
            d += b2f(Q1[(q1b + (size_t)(4*y+dy)*64 + (4*x+dx))*768 + 512 + c]);
    acc += d * 0.0625f;
    size_t q2b = (size_t)b * 1024;
    float e = 0.f;
#pragma unroll
    for (int dy = 0; dy < 2; ++dy)
#pragma unroll
        for (int dx = 0; dx < 2; ++dx)
            e += b2f(Q2[(q2b + (size_t)(2*y+dy)*32 + (2*x+dx))*768 + 512 + c]);
    acc += 0.25f * e;
    acc += bias[c];
    s3o[(size_t)p * 256 + c] = f2b(acc);
}

// ---------------------------------------------------------------------------
// Windowed MHA: one wave per (batch, window, head). nt=16 tokens, hd=32.
//  S^T = mfma(Kfrag, Qfrag)  -> scale + rel-pos bias -> softmax over j
//  (4 regs in-lane + shfl_xor 16/32) -> P packed bf16, shfl-redistributed to
//  B-operand layout -> O^T halves = mfma(V^T_half, P)  (K zero-padded 16->32).
// ---------------------------------------------------------------------------
__global__ __launch_bounds__(256)
void attn_kernel(const ushort_t* __restrict__ qkv, ushort_t* __restrict__ outp,
                 const float* __restrict__ rpb, int Wpix, int nwx, int nw,
                 int npix, int totwaves)
{
    int gw   = (blockIdx.x * 256 + threadIdx.x) >> 6;
    int lane = threadIdx.x & 63;
    if (gw >= totwaves) return;
    int h   = gw & 7;
    int win = (gw >> 3) % nw;
    int b   = gw / (nw * 8);
    int wy = win / nwx, wx = win % nwx;
    int i = lane & 15, g = lane >> 4;
    size_t rowbase = (size_t)b * npix;
    int py = wy * 4, px = wx * 4;

    size_t rowi = (rowbase + (size_t)(py + (i >> 2)) * Wpix + px + (i & 3)) * 768;
    int koff = h * 32 + 8 * g;
    short8 kf = *(const short8*)(qkv + rowi + 256 + koff);   // A: K  (row=j)
    short8 qf = *(const short8*)(qkv + rowi + koff);         // B: Q^T (col=i)
    f32x4 stv = {0.f, 0.f, 0.f, 0.f};
    stv = __builtin_amdgcn_mfma_f32_16x16x32_bf16(kf, qf, stv, 0, 0, 0);

    const float scale = 0.17677669529663687f;   // 32^-0.5
    float sv[4], p[4];
    float m = -1e30f;
#pragma unroll
    for (int r = 0; r < 4; ++r) {
        int j  = 4 * g + r;
        int dy = (i >> 2) - (j >> 2) + 3;
        int dx = (i & 3)  - (j & 3)  + 3;
        sv[r] = stv[r] * scale + rpb[(dy * 7 + dx) * 8 + h];
        m = fmaxf(m, sv[r]);
    }
    m = fmaxf(m, __shfl_xor(m, 16));
    m = fmaxf(m, __shfl_xor(m, 32));
    float sum = 0.f;
#pragma unroll
    for (int r = 0; r < 4; ++r) { p[r] = __expf(sv[r] - m); sum += p[r]; }
    sum += __shfl_xor(sum, 16);
    sum += __shfl_xor(sum, 32);
    float inv = 1.f / sum;
    unsigned pa = (unsigned)f2b(p[0]*inv) | ((unsigned)f2b(p[1]*inv) << 16);
    unsigned pb = (unsigned)f2b(p[2]*inv) | ((unsigned)f2b(p[3]*inv) << 16);

    // B-operand for PV: lane needs P[i][8g..8g+8); rows live at lanes i+32g, i+32g+16
    int srcA = (i + 32 * g) & 63;
    int srcB = (i + 32 * g + 16) & 63;
    unsigned a0 = (unsigned)__shfl((int)pa, srcA);
    unsigned a1 = (unsigned)__shfl((int)pb, srcA);
    unsigned b0 = (unsigned)__shfl((int)pa, srcB);
    unsigned b1 = (unsigned)__shfl((int)pb, srcB);
    if (g >= 2) { a0 = a1 = b0 = b1 = 0; }      // K zero-pad (j >= 16)
    union { unsigned u[4]; short8 v; } pf;
    pf.u[0] = a0; pf.u[1] = a1; pf.u[2] = b0; pf.u[3] = b1;

    size_t orow = (rowbase + (size_t)(py + (i >> 2)) * Wpix + px + (i & 3)) * 256;
#pragma unroll
    for (int h2 = 0; h2 < 2; ++h2) {
        union { ushort_t us[8]; short8 v; } vt;
#pragma unroll
        for (int jj = 0; jj < 8; ++jj) vt.us[jj] = 0;
        if (g < 2) {   // A: V^T half, row=d', k=token (k>=16 zero)
#pragma unroll
            for (int jj = 0; jj < 8; ++jj) {
                int t = 8 * g + jj;
                size_t rv = (rowbase + (size_t)(py + (t >> 2)) * Wpix + px + (t & 3)) * 768;
                vt.us[jj] = qkv[rv + 512 + h * 32 + h2 * 16 + i];
            }
        }
        f32x4 ov = {0.f, 0.f, 0.f, 0.f};
        ov = __builtin_amdgcn_mfma_f32_16x16x32_bf16(vt.v, pf.v, ov, 0, 0, 0);
        ushort4 st;
        st.x = f2b(ov[0]); st.y = f2b(ov[1]); st.z = f2b(ov[2]); st.w = f2b(ov[3]);
        *(ushort4*)(outp + orow + h * 32 + h2 * 16 + 4 * g) = st;
    }
}

// ===========================================================================
extern "C" void kernel_launch(void* const* d_in, const int* in_sizes, int n_in,
                              void* d_out, int out_size, void* d_ws, size_t ws_size,
                              hipStream_t stream)
{
    (void)in_sizes; (void)n_in; (void)out_size; (void)ws_size;
    const float* x    = (const float*)d_in[0];
    const float* n1g  = (const float*)d_in[1];
    const float* n1b  = (const float*)d_in[2];
    const float* c1w  = (const float*)d_in[3];
    const float* c1b  = (const float*)d_in[4];
    const float* c2w  = (const float*)d_in[5];
    const float* c2b  = (const float*)d_in[6];
    const float* c3w  = (const float*)d_in[7];
    const float* c3b  = (const float*)d_in[8];
    const float* q1w  = (const float*)d_in[9];
    const float* q1b  = (const float*)d_in[10];
    const float* p1w  = (const float*)d_in[11];
    const float* p1b  = (const float*)d_in[12];
    const float* rpb1 = (const float*)d_in[13];
    const float* q2w  = (const float*)d_in[14];
    const float* q2b  = (const float*)d_in[15];
    const float* p2w  = (const float*)d_in[16];
    const float* p2b  = (const float*)d_in[17];
    const float* rpb2 = (const float*)d_in[18];
    const float* q3w  = (const float*)d_in[19];
    const float* q3b  = (const float*)d_in[20];
    const float* p3w  = (const float*)d_in[21];
    const float* p3b  = (const float*)d_in[22];
    const float* rpb3 = (const float*)d_in[23];
    const float* n3g  = (const float*)d_in[24];
    const float* n3b  = (const float*)d_in[25];
    const float* ffw  = (const float*)d_in[26];
    const float* ffb  = (const float*)d_in[27];
    float* out = (float*)d_out;

    const int M1 = 32 * 4096, M2 = 32 * 1024, M3 = 32 * 256;
    const int MT = M1 + M2 + M3;            // 172032 tokens total

    // ---- workspace layout (bytes) ----
    char* ws = (char*)d_ws;
    // region A (88,080,384 B): xn1|xn2|xn3, later reused as attn1|attn2|attn3
    ushort_t* xn1 = (ushort_t*)ws;
    ushort_t* xn2 = xn1 + (size_t)M1 * 256;
    ushort_t* xn3 = xn2 + (size_t)M2 * 256;
    ushort_t* at1 = xn1; ushort_t* at2 = xn2; ushort_t* at3 = xn3;
    // region B (264,241,152 B): Q1|Q2|Q3, later reused as qkv1|qkv2|qkv3
    ushort_t* Q1 = (ushort_t*)(ws + 88080384);
    ushort_t* Q2 = Q1 + (size_t)M1 * 768;
    ushort_t* Q3 = Q2 + (size_t)M2 * 768;
    ushort_t* kv1 = Q1; ushort_t* kv2 = Q2; ushort_t* kv3 = Q3;
    // region C (88,080,384 B): s1|s2|s3, later reused as ln2 (same total size)
    ushort_t* s1 = (ushort_t*)(ws + 88080384 + 264241152);
    ushort_t* s2 = s1 + (size_t)M1 * 256;
    ushort_t* s3 = s2 + (size_t)M2 * 256;
    ushort_t* ln2 = s1;
    // region W (~2.9 MB): bf16 weights
    ushort_t* Wf  = (ushort_t*)(ws + 88080384 + 264241152 + 88080384);
    ushort_t* Wq  = Wf + 3*768*256;
    ushort_t* Wp  = Wq + 3*768*256;
    ushort_t* Wff = Wp + 3*256*256;

    // 0. weight repack (1,441,792 elements = 5632 blocks x 256)
    repack<<<5632, 256, 0, stream>>>(c1w, c2w, c3w, q1w, q2w, q3w,
                                     p1w, p2w, p3w, ffw, Wf, Wq, Wp, Wff);
    // 1. LN1 -> xn (split per scale)
    ln_kernel<true><<<MT/4, 256, 0, stream>>>(x, n1g, n1b, xn1, xn2, xn3, MT);
    // 2. fusion GEMMs: Q_j = xn_j @ Wf_j^T   (Nout=768)
    gemm_k256<0,false><<<dim3(6, M1/128), 256, 0, stream>>>(xn1, Wf,          nullptr, nullptr, Q1, M1, 768, 0, 0, 0);
    gemm_k256<0,false><<<dim3(6, M2/128), 256, 0, stream>>>(xn2, Wf+196608,   nullptr, nullptr, Q2, M2, 768, 0, 0, 0);
    gemm_k256<0,false><<<dim3(6, M3/128), 256, 0, stream>>>(xn3, Wf+393216,   nullptr, nullptr, Q3, M3, 768, 0, 0, 0);
    // 3. resample + sum (+conv bias) -> s_i
    fuse1<<<M1, 256, 0, stream>>>(Q1, Q2, Q3, c1b, s1);
    fuse2<<<M2, 256, 0, stream>>>(Q1, Q2, Q3, c2b, s2);
    fuse3<<<M3, 256, 0, stream>>>(Q1, Q2, Q3, c3b, s3);
    // 4. QKV GEMMs (bias) -> qkv (reuses Q region)
    gemm_k256<0,true><<<dim3(6, M1/128), 256, 0, stream>>>(s1, Wq,         q1b, nullptr, kv1, M1, 768, 0, 0, 0);
    gemm_k256<0,true><<<dim3(6, M2/128), 256, 0, stream>>>(s2, Wq+196608,  q2b, nullptr, kv2, M2, 768, 0, 0, 0);
    gemm_k256<0,true><<<dim3(6, M3/128), 256, 0, stream>>>(s3, Wq+393216,  q3b, nullptr, kv3, M3, 768, 0, 0, 0);
    // 5. windowed attention (reuses xn region for output)
    attn_kernel<<<16384, 256, 0, stream>>>(kv1, at1, rpb1, 64, 16, 256, 4096, 65536);
    attn_kernel<<< 4096, 256, 0, stream>>>(kv2, at2, rpb2, 32,  8,  64, 1024, 16384);
    attn_kernel<<< 1024, 256, 0, stream>>>(kv3, at3, rpb3, 16,  4,  16,  256,  4096);
    // 6. proj GEMMs + residual -> d_out (f32, token-remapped rows)
    gemm_k256<1,true><<<dim3(2, M1/128), 256, 0, stream>>>(at1, Wp,        p1b, x, out, M1, 256, 4096, 5376, 0);
    gemm_k256<1,true><<<dim3(2, M2/128), 256, 0, stream>>>(at2, Wp+65536,  p2b, x, out, M2, 256, 1024, 5376, 4096);
    gemm_k256<1,true><<<dim3(2, M3/128), 256, 0, stream>>>(at3, Wp+131072, p3b, x, out, M3, 256,  256, 5376, 5120);
    // 7. LN2 on d_out -> ln2 (reuses s region)
    ln_kernel<false><<<MT/4, 256, 0, stream>>>(out, n3g, n3b, ln2, nullptr, nullptr, MT);
    // 8. FFN GEMM, accumulate into d_out
    gemm_k256<2,true><<<dim3(2, MT/128), 256, 0, stream>>>(ln2, Wff, ffb, nullptr, out, MT, 256, MT, 0, 0);
}

// Round 4
// 1057.060 us; speedup vs baseline: 1.2381x; 1.2381x over previous
//
#include <hip/hip_runtime.h>

// ============================================================================
// R3 (resubmit): restructured fusion path.
//  LN1 -> xn1 / A2cat(col256) / A3cat(col512)  (strided split write)
//  down1: xn1 -> A2cat(col0);  down2: A2cat -> A3cat(col0,col256)
//  small GEMMs: Q21 (M2), Q31/Q32 (M3)   [commuted: downsample BEFORE conv]
//  G1: xn1@W11+b -> Q11 ; G2: A2cat@Wc2[0:512]+b -> s2 ; G3: A3cat@Wc3+b -> s3
//  fuse1v: s1 = Q11 + up(Q21) + upup(Q31)   (short8-vectorized)
//  fuse2v: s2 += up(Q32)                    (short8-vectorized)
//  QKV GEMMs -> attn -> proj(+resid,f32) -> LN2 -> FFN accumulate.
// ============================================================================

typedef unsigned short ushort_t;      // bf16 bits
typedef unsigned int   uint32;
typedef __attribute__((ext_vector_type(8))) short short8;   // 8 x bf16 (4 VGPR)
typedef __attribute__((ext_vector_type(4))) float f32x4;

#define GLOBAL_AS __attribute__((address_space(1)))
#define LDS_AS    __attribute__((address_space(3)))

__device__ __forceinline__ float b2f(ushort_t h) {
    union { uint32 u; float f; } x; x.u = ((uint32)h) << 16; return x.f;
}
__device__ __forceinline__ ushort_t f2b(float f) {
    union { float f; uint32 u; } x; x.f = f;
    uint32 u = x.u;
    return (ushort_t)((u + 0x7FFFu + ((u >> 16) & 1u)) >> 16);   // RNE
}
__device__ __forceinline__ void async_ld16(const void* g, void* l) {
    __builtin_amdgcn_global_load_lds((const GLOBAL_AS uint32*)g, (LDS_AS uint32*)l, 16, 0, 0);
}

// ---------------------------------------------------------------------------
// LayerNorm: one wave per token (C=256). SPLIT: write xn1 (stride 256),
// A2cat col256 (stride 512), A3cat col512 (stride 768).
// ---------------------------------------------------------------------------
template<bool SPLIT>
__global__ __launch_bounds__(256)
void ln_kernel(const float* __restrict__ x, const float* __restrict__ g,
               const float* __restrict__ bb,
               ushort_t* d0, ushort_t* d1, ushort_t* d2, int ntok)
{
    int wid  = blockIdx.x * 4 + (threadIdx.x >> 6);
    int lane = threadIdx.x & 63;
    if (wid >= ntok) return;
    const float* row = x + (size_t)wid * 256;
    float4 v = *(const float4*)(row + lane * 4);
    float s  = v.x + v.y + v.z + v.w;
    float s2 = v.x*v.x + v.y*v.y + v.z*v.z + v.w*v.w;
#pragma unroll
    for (int mask = 1; mask < 64; mask <<= 1) {
        s  += __shfl_xor(s,  mask);
        s2 += __shfl_xor(s2, mask);
    }
    float mean = s * (1.f/256.f);
    float var  = s2 * (1.f/256.f) - mean*mean;
    float rstd = rsqrtf(var + 1e-5f);
    ushort_t* dst;
    if (SPLIT) {
        int b = wid / 5376, n = wid % 5376;
        if      (n < 4096) dst = d0 + ((size_t)b*4096 + n)        * 256;
        else if (n < 5120) dst = d1 + ((size_t)b*1024 + (n-4096)) * 512;
        else               dst = d2 + ((size_t)b*256  + (n-5120)) * 768;
    } else {
        dst = d0 + (size_t)wid * 256;
    }
    int c = lane * 4;
    float4 gg = *(const float4*)(g  + c);
    float4 bv = *(const float4*)(bb + c);
    ushort4 o;
    o.x = f2b((v.x-mean)*rstd*gg.x + bv.x);
    o.y = f2b((v.y-mean)*rstd*gg.y + bv.y);
    o.z = f2b((v.z-mean)*rstd*gg.z + bv.z);
    o.w = f2b((v.w-mean)*rstd*gg.w + bv.w);
    *(ushort4*)(dst + c) = o;
}

// ---------------------------------------------------------------------------
// Weight cast to bf16, all matrices verbatim (row-major as given).
// Layout: Wc1|Wc2|Wc3 (each 256x768), Wq1|Wq2|Wq3 (768x256),
//         Wp1|Wp2|Wp3 (256x256), Wff (256x256).  1,441,792 elements.
// ---------------------------------------------------------------------------
__global__ __launch_bounds__(256)
void repack(const float* c1, const float* c2, const float* c3,
            const float* q1, const float* q2, const float* q3,
            const float* p1, const float* p2, const float* p3,
            const float* fw, ushort_t* W)
{
    int idx = blockIdx.x * 256 + threadIdx.x;
    const float* src; int off;
    if      (idx <  196608) { src = c1; off = idx; }
    else if (idx <  393216) { src = c2; off = idx -  196608; }
    else if (idx <  589824) { src = c3; off = idx -  393216; }
    else if (idx <  786432) { src = q1; off = idx -  589824; }
    else if (idx <  983040) { src = q2; off = idx -  786432; }
    else if (idx < 1179648) { src = q3; off = idx -  983040; }
    else if (idx < 1245184) { src = p1; off = idx - 1179648; }
    else if (idx < 1310720) { src = p2; off = idx - 1245184; }
    else if (idx < 1376256) { src = p3; off = idx - 1310720; }
    else                    { src = fw; off = idx - 1376256; }
    W[idx] = f2b(src[off]);
}

// ---------------------------------------------------------------------------
// Downsample kernels (2x2 mean), short8-vectorized (8 ch/thread).
// ---------------------------------------------------------------------------
__global__ __launch_bounds__(256)
void down1(const ushort_t* __restrict__ xn1, ushort_t* __restrict__ A2cat)
{
    int t = blockIdx.x * 256 + threadIdx.x;     // M2*32 threads
    int p = t >> 5, c0 = (t & 31) * 8;
    int b = p >> 10, pix = p & 1023;
    int y = pix >> 5, x = pix & 31;
    size_t base = (size_t)b * 4096;
    float acc[8] = {0,0,0,0,0,0,0,0};
#pragma unroll
    for (int dy = 0; dy < 2; ++dy)
#pragma unroll
    for (int dx = 0; dx < 2; ++dx) {
        short8 v = *(const short8*)(xn1 + (base + (size_t)(2*y+dy)*64 + (2*x+dx)) * 256 + c0);
#pragma unroll
        for (int j = 0; j < 8; ++j) acc[j] += b2f((ushort_t)v[j]);
    }
    union { ushort_t us[8]; short8 v; } o;
#pragma unroll
    for (int j = 0; j < 8; ++j) o.us[j] = f2b(acc[j] * 0.25f);
    *(short8*)(A2cat + (size_t)p * 512 + c0) = o.v;
}

__global__ __launch_bounds__(256)
void down2(const ushort_t* __restrict__ A2cat, ushort_t* __restrict__ A3cat)
{
    int t = blockIdx.x * 256 + threadIdx.x;     // M3*32*2 threads
    int half = t >> 18;                          // 0: xdd1 (col0), 1: xd2 (col256)
    int r = t & 262143;
    int p = r >> 5, c0 = (r & 31) * 8;
    int b = p >> 8, pix = p & 255;
    int y = pix >> 4, x = pix & 15;
    int co = half * 256;
    size_t base = (size_t)b * 1024;
    float acc[8] = {0,0,0,0,0,0,0,0};
#pragma unroll
    for (int dy = 0; dy < 2; ++dy)
#pragma unroll
    for (int dx = 0; dx < 2; ++dx) {
        short8 v = *(const short8*)(A2cat + (base + (size_t)(2*y+dy)*32 + (2*x+dx)) * 512 + co + c0);
#pragma unroll
        for (int j = 0; j < 8; ++j) acc[j] += b2f((ushort_t)v[j]);
    }
    union { ushort_t us[8]; short8 v; } o;
#pragma unroll
    for (int j = 0; j < 8; ++j) o.us[j] = f2b(acc[j] * 0.25f);
    *(short8*)(A3cat + (size_t)p * 768 + co + c0) = o.v;
}

// ---------------------------------------------------------------------------
// GEMM: out(M,N) = A(M,K;lda) @ Bw(N,K;ldb)^T  [+bias][+resid]
// 128x128 tile, BK=64, 4 waves (2x2), each wave 64x64 via 4x4 mfma 16x16x32.
// MODE 0: bf16 store (row stride Nout). MODE 1: f32 store to remapped token
//   rows (+bias+resid). MODE 2: f32 accumulate (+bias), identity rows.
// ---------------------------------------------------------------------------
template<int MODE, bool HAS_BIAS>
__global__ __launch_bounds__(256)
void gemm_bt(const ushort_t* __restrict__ A, int lda,
             const ushort_t* __restrict__ Bw, int ldb, int K,
             const float* __restrict__ bias, const float* __restrict__ resid,
             void* __restrict__ outp, int Nout,
             int n_per_b, int N_total, int off)
{
    __shared__ ushort_t As[128][64];
    __shared__ ushort_t Bs[128][64];
    int lane = threadIdx.x & 63;
    int w    = threadIdx.x >> 6;
    int m0 = blockIdx.y * 128;
    int n0 = blockIdx.x * 128;
    int wm = w >> 1, wn = w & 1;

    f32x4 acc[4][4];
#pragma unroll
    for (int m = 0; m < 4; ++m)
#pragma unroll
        for (int n = 0; n < 4; ++n) acc[m][n] = f32x4{0.f,0.f,0.f,0.f};

    int sr = lane >> 3;          // row within 8-row staging chunk
    int sc = (lane & 7) * 8;     // col (elements)

    for (int k0 = 0; k0 < K; k0 += 64) {
        __syncthreads();
#pragma unroll
        for (int q = 0; q < 4; ++q) {
            int rr = (w*4 + q) * 8;
            const ushort_t* ga = A  + (size_t)(m0 + rr + sr) * lda + (k0 + sc);
            const ushort_t* gb = Bw + (size_t)(n0 + rr + sr) * ldb + (k0 + sc);
            async_ld16(ga, &As[rr][0]);
            async_ld16(gb, &Bs[rr][0]);
        }
        __syncthreads();
        int row = lane & 15;
        int kof = 8 * (lane >> 4);
#pragma unroll
        for (int kk = 0; kk < 64; kk += 32) {
            short8 af[4], bf[4];
#pragma unroll
            for (int m = 0; m < 4; ++m)
                af[m] = *(const short8*)&As[wm*64 + m*16 + row][kk + kof];
#pragma unroll
            for (int n = 0; n < 4; ++n)
                bf[n] = *(const short8*)&Bs[wn*64 + n*16 + row][kk + kof];
#pragma unroll
            for (int m = 0; m < 4; ++m)
#pragma unroll
                for (int n = 0; n < 4; ++n)
                    acc[m][n] = __builtin_amdgcn_mfma_f32_16x16x32_bf16(
                        af[m], bf[n], acc[m][n], 0, 0, 0);
        }
    }

    int cr = (lane >> 4) * 4;
    int cc = lane & 15;
#pragma unroll
    for (int m = 0; m < 4; ++m) {
#pragma unroll
        for (int r = 0; r < 4; ++r) {
            int grow = m0 + wm*64 + m*16 + cr + r;
            size_t orow;
            if (MODE == 1) {
                int bidx = grow / n_per_b;
                int t    = grow - bidx * n_per_b;
                orow = (size_t)bidx * N_total + off + t;
            } else {
                orow = (size_t)grow;
            }
#pragma unroll
            for (int n = 0; n < 4; ++n) {
                int col = n0 + wn*64 + n*16 + cc;
                float v = acc[m][n][r];
                if (HAS_BIAS) v += bias[col];
                if (MODE == 0) {
                    ((ushort_t*)outp)[(size_t)grow * Nout + col] = f2b(v);
                } else if (MODE == 1) {
                    float* o = (float*)outp;
                    v += resid[orow * 256 + col];
                    o[orow * 256 + col] = v;
                } else {
                    float* o = (float*)outp;
                    o[orow * 256 + col] += v;
                }
            }
        }
    }
}

// ---------------------------------------------------------------------------
// Bilinear 2x up taps: half-pixel centers, edge clamp (== jax at exact 2x).
// ---------------------------------------------------------------------------
__device__ __forceinline__ void up_taps(int i, int S, int& j0, int& j1,
                                        float& w0, float& w1)
{
    int t = i >> 1;
    if (i & 1) { j0 = t; j1 = (t+1 < S) ? t+1 : S-1; w0 = 0.75f; w1 = 0.25f; }
    else       { j0 = (t > 0) ? t-1 : 0; j1 = t;     w0 = 0.25f; w1 = 0.75f; }
}

// s1 = Q11 + up(Q21) + up(up(Q31)); bias already in Q11 (G1). short8-vectorized.
__global__ __launch_bounds__(256)
void fuse1v(const ushort_t* __restrict__ Q11, const ushort_t* __restrict__ Q21,
            const ushort_t* __restrict__ Q31, ushort_t* __restrict__ s1o)
{
    int t = threadIdx.x;
    int p = blockIdx.x * 8 + (t >> 5);
    int c0 = (t & 31) * 8;
    int b = p >> 12, pix = p & 4095;
    int y = pix >> 6, x = pix & 63;
    float acc[8];
    {
        short8 v = *(const short8*)(Q11 + (size_t)p * 256 + c0);
#pragma unroll
        for (int j = 0; j < 8; ++j) acc[j] = b2f((ushort_t)v[j]);
    }
    int y0,y1,x0,x1; float wy0,wy1,wx0,wx1;
    up_taps(y, 32, y0, y1, wy0, wy1);
    up_taps(x, 32, x0, x1, wx0, wx1);
    const int   ty[2] = {y0, y1}; const float wyv[2] = {wy0, wy1};
    const int   tx[2] = {x0, x1}; const float wxv[2] = {wx0, wx1};
    size_t q2b = (size_t)b * 1024;
#pragma unroll
    for (int ay = 0; ay < 2; ++ay)
#pragma unroll
    for (int ax = 0; ax < 2; ++ax) {
        float wgt = wyv[ay] * wxv[ax];
        short8 v = *(const short8*)(Q21 + (q2b + (size_t)ty[ay]*32 + tx[ax]) * 256 + c0);
#pragma unroll
        for (int j = 0; j < 8; ++j) acc[j] += wgt * b2f((ushort_t)v[j]);
    }
    size_t q3b = (size_t)b * 256;
#pragma unroll
    for (int ay = 0; ay < 2; ++ay) {
        int sy0, sy1; float wsy0, wsy1;
        up_taps(ty[ay], 16, sy0, sy1, wsy0, wsy1);
        const int sy[2] = {sy0, sy1}; const float wsy[2] = {wsy0, wsy1};
#pragma unroll
        for (int ax = 0; ax < 2; ++ax) {
            float wm = wyv[ay] * wxv[ax];
            int sx0, sx1; float wsx0, wsx1;
            up_taps(tx[ax], 16, sx0, sx1, wsx0, wsx1);
            const int sx[2] = {sx0, sx1}; const float wsx[2] = {wsx0, wsx1};
#pragma unroll
            for (int iy = 0; iy < 2; ++iy)
#pragma unroll
            for (int ix = 0; ix < 2; ++ix) {
                float wgt = wm * wsy[iy] * wsx[ix];
                short8 v = *(const short8*)(Q31 + (q3b + (size_t)sy[iy]*16 + sx[ix]) * 256 + c0);
#pragma unroll
                for (int j = 0; j < 8; ++j) acc[j] += wgt * b2f((ushort_t)v[j]);
            }
        }
    }
    union { ushort_t us[8]; short8 v; } o;
#pragma unroll
    for (int j = 0; j < 8; ++j) o.us[j] = f2b(acc[j]);
    *(short8*)(s1o + (size_t)p * 256 + c0) = o.v;
}

// s2 += up(Q32), in place. short8-vectorized.
__global__ __launch_bounds__(256)
void fuse2v(ushort_t* __restrict__ s2, const ushort_t* __restrict__ Q32)
{
    int t = blockIdx.x * 256 + threadIdx.x;   // M2*32 threads
    int p = t >> 5, c0 = (t & 31) * 8;
    int b = p >> 10, pix = p & 1023;
    int y = pix >> 5, x = pix & 31;
    float acc[8];
    {
        short8 v = *(const short8*)(s2 + (size_t)p * 256 + c0);
#pragma unroll
        for (int j = 0; j < 8; ++j) acc[j] = b2f((ushort_t)v[j]);
    }
    int y0,y1,x0,x1; float wy0,wy1,wx0,wx1;
    up_taps(y, 16, y0, y1, wy0, wy1);
    up_taps(x, 16, x0, x1, wx0, wx1);
    const int   ty[2] = {y0, y1}; const float wyv[2] = {wy0, wy1};
    const int   tx[2] = {x0, x1}; const float wxv[2] = {wx0, wx1};
    size_t q3b = (size_t)b * 256;
#pragma unroll
    for (int ay = 0; ay < 2; ++ay)
#pragma unroll
    for (int ax = 0; ax < 2; ++ax) {
        float wgt = wyv[ay] * wxv[ax];
        short8 v = *(const short8*)(Q32 + (q3b + (size_t)ty[ay]*16 + tx[ax]) * 256 + c0);
#pragma unroll
        for (int j = 0; j < 8; ++j) acc[j] += wgt * b2f((ushort_t)v[j]);
    }
    union { ushort_t us[8]; short8 v; } o;
#pragma unroll
    for (int j = 0; j < 8; ++j) o.us[j] = f2b(acc[j]);
    *(short8*)(s2 + (size_t)p * 256 + c0) = o.v;
}

// ---------------------------------------------------------------------------
// Windowed MHA: one wave per (batch, window, head). nt=16 tokens, hd=32.
// ---------------------------------------------------------------------------
__global__ __launch_bounds__(256)
void attn_kernel(const ushort_t* __restrict__ qkv, ushort_t* __restrict__ outp,
                 const float* __restrict__ rpb, int Wpix, int nwx, int nw,
                 int npix, int totwaves)
{
    int gw   = (blockIdx.x * 256 + threadIdx.x) >> 6;
    int lane = threadIdx.x & 63;
    if (gw >= totwaves) return;
    int h   = gw & 7;
    int win = (gw >> 3) % nw;
    int b   = gw / (nw * 8);
    int wy = win / nwx, wx = win % nwx;
    int i = lane & 15, g = lane >> 4;
    size_t rowbase = (size_t)b * npix;
    int py = wy * 4, px = wx * 4;

    size_t rowi = (rowbase + (size_t)(py + (i >> 2)) * Wpix + px + (i & 3)) * 768;
    int koff = h * 32 + 8 * g;
    short8 kf = *(const short8*)(qkv + rowi + 256 + koff);   // A: K  (row=j)
    short8 qf = *(const short8*)(qkv + rowi + koff);         // B: Q^T (col=i)
    f32x4 stv = {0.f, 0.f, 0.f, 0.f};
    stv = __builtin_amdgcn_mfma_f32_16x16x32_bf16(kf, qf, stv, 0, 0, 0);

    const float scale = 0.17677669529663687f;   // 32^-0.5
    float sv[4], p[4];
    float m = -1e30f;
#pragma unroll
    for (int r = 0; r < 4; ++r) {
        int j  = 4 * g + r;
        int dy = (i >> 2) - (j >> 2) + 3;
        int dx = (i & 3)  - (j & 3)  + 3;
        sv[r] = stv[r] * scale + rpb[(dy * 7 + dx) * 8 + h];
        m = fmaxf(m, sv[r]);
    }
    m = fmaxf(m, __shfl_xor(m, 16));
    m = fmaxf(m, __shfl_xor(m, 32));
    float sum = 0.f;
#pragma unroll
    for (int r = 0; r < 4; ++r) { p[r] = __expf(sv[r] - m); sum += p[r]; }
    sum += __shfl_xor(sum, 16);
    sum += __shfl_xor(sum, 32);
    float inv = 1.f / sum;
    unsigned pa = (unsigned)f2b(p[0]*inv) | ((unsigned)f2b(p[1]*inv) << 16);
    unsigned pb = (unsigned)f2b(p[2]*inv) | ((unsigned)f2b(p[3]*inv) << 16);

    int srcA = (i + 32 * g) & 63;
    int srcB = (i + 32 * g + 16) & 63;
    unsigned a0 = (unsigned)__shfl((int)pa, srcA);
    unsigned a1 = (unsigned)__shfl((int)pb, srcA);
    unsigned b0 = (unsigned)__shfl((int)pa, srcB);
    unsigned b1 = (unsigned)__shfl((int)pb, srcB);
    if (g >= 2) { a0 = a1 = b0 = b1 = 0; }      // K zero-pad (j >= 16)
    union { unsigned u[4]; short8 v; } pf;
    pf.u[0] = a0; pf.u[1] = a1; pf.u[2] = b0; pf.u[3] = b1;

    size_t orow = (rowbase + (size_t)(py + (i >> 2)) * Wpix + px + (i & 3)) * 256;
#pragma unroll
    for (int h2 = 0; h2 < 2; ++h2) {
        union { ushort_t us[8]; short8 v; } vt;
#pragma unroll
        for (int jj = 0; jj < 8; ++jj) vt.us[jj] = 0;
        if (g < 2) {   // A: V^T half, row=d', k=token (k>=16 zero)
#pragma unroll
            for (int jj = 0; jj < 8; ++jj) {
                int t = 8 * g + jj;
                size_t rv = (rowbase + (size_t)(py + (t >> 2)) * Wpix + px + (t & 3)) * 768;
                vt.us[jj] = qkv[rv + 512 + h * 32 + h2 * 16 + i];
            }
        }
        f32x4 ov = {0.f, 0.f, 0.f, 0.f};
        ov = __builtin_amdgcn_mfma_f32_16x16x32_bf16(vt.v, pf.v, ov, 0, 0, 0);
        ushort4 st;
        st.x = f2b(ov[0]); st.y = f2b(ov[1]); st.z = f2b(ov[2]); st.w = f2b(ov[3]);
        *(ushort4*)(outp + orow + h * 32 + h2 * 16 + 4 * g) = st;
    }
}

// ===========================================================================
extern "C" void kernel_launch(void* const* d_in, const int* in_sizes, int n_in,
                              void* d_out, int out_size, void* d_ws, size_t ws_size,
                              hipStream_t stream)
{
    (void)in_sizes; (void)n_in; (void)out_size; (void)ws_size;
    const float* x    = (const float*)d_in[0];
    const float* n1g  = (const float*)d_in[1];
    const float* n1b  = (const float*)d_in[2];
    const float* c1w  = (const float*)d_in[3];
    const float* c1b  = (const float*)d_in[4];
    const float* c2w  = (const float*)d_in[5];
    const float* c2b  = (const float*)d_in[6];
    const float* c3w  = (const float*)d_in[7];
    const float* c3b  = (const float*)d_in[8];
    const float* q1w  = (const float*)d_in[9];
    const float* q1b  = (const float*)d_in[10];
    const float* p1w  = (const float*)d_in[11];
    const float* p1b  = (const float*)d_in[12];
    const float* rpb1 = (const float*)d_in[13];
    const float* q2w  = (const float*)d_in[14];
    const float* q2b  = (const float*)d_in[15];
    const float* p2w  = (const float*)d_in[16];
    const float* p2b  = (const float*)d_in[17];
    const float* rpb2 = (const float*)d_in[18];
    const float* q3w  = (const float*)d_in[19];
    const float* q3b  = (const float*)d_in[20];
    const float* p3w  = (const float*)d_in[21];
    const float* p3b  = (const float*)d_in[22];
    const float* rpb3 = (const float*)d_in[23];
    const float* n3g  = (const float*)d_in[24];
    const float* n3b  = (const float*)d_in[25];
    const float* ffw  = (const float*)d_in[26];
    const float* ffb  = (const float*)d_in[27];
    float* out = (float*)d_out;

    const int M1 = 32 * 4096, M2 = 32 * 1024, M3 = 32 * 256;
    const int MT = M1 + M2 + M3;            // 172032 tokens total

    // ---- workspace layout ----
    // R1 (264,241,152 B): xn1|A2cat|A3cat|Q11|Q21|Q31|Q32  -> later qkv1|2|3 -> later ln2
    // R2 ( 88,080,384 B): s1|s2|s3 -> later at1|at2|at3
    // W  (  2,883,584 B): bf16 weights
    char* ws = (char*)d_ws;
    ushort_t* R1 = (ushort_t*)ws;
    ushort_t* xn1   = R1;                       // M1*256
    ushort_t* A2cat = R1 + 33554432;            // M2*512
    ushort_t* A3cat = R1 + 50331648;            // M3*768
    ushort_t* Q11   = R1 + 56623104;            // M1*256
    ushort_t* Q21   = R1 + 90177536;            // M2*256
    ushort_t* Q31   = R1 + 98566144;            // M3*256
    ushort_t* Q32   = R1 + 100663296;           // M3*256
    ushort_t* kv1 = R1;                         // M1*768
    ushort_t* kv2 = kv1 + (size_t)M1 * 768;
    ushort_t* kv3 = kv2 + (size_t)M2 * 768;
    ushort_t* ln2 = R1;                         // MT*256
    ushort_t* R2 = (ushort_t*)(ws + 264241152);
    ushort_t* s1 = R2;
    ushort_t* s2 = R2 + (size_t)M1 * 256;
    ushort_t* s3 = s2 + (size_t)M2 * 256;
    ushort_t* at1 = s1; ushort_t* at2 = s2; ushort_t* at3 = s3;
    ushort_t* W   = (ushort_t*)(ws + 264241152 + 88080384);
    ushort_t* Wc1 = W;                 // 256x768
    ushort_t* Wc2 = W + 196608;
    ushort_t* Wc3 = W + 393216;
    ushort_t* Wq1 = W + 589824;        // 768x256
    ushort_t* Wq2 = W + 786432;
    ushort_t* Wq3 = W + 983040;
    ushort_t* Wp1 = W + 1179648;       // 256x256
    ushort_t* Wp2 = W + 1245184;
    ushort_t* Wp3 = W + 1310720;
    ushort_t* Wff = W + 1376256;

    // 0. weight cast
    repack<<<5632, 256, 0, stream>>>(c1w, c2w, c3w, q1w, q2w, q3w,
                                     p1w, p2w, p3w, ffw, W);
    // 1. LN1 -> xn1 / A2cat(col256) / A3cat(col512)
    ln_kernel<true><<<MT/4, 256, 0, stream>>>(x, n1g, n1b, xn1, A2cat + 256, A3cat + 512, MT);
    // 2. downsample chain (commuted before conv)
    down1<<<4096, 256, 0, stream>>>(xn1, A2cat);
    down2<<<2048, 256, 0, stream>>>(A2cat, A3cat);
    // 3. small per-source GEMMs for cross-scale up contributions (no bias)
    gemm_bt<0,false><<<dim3(2, 256), 256, 0, stream>>>(A2cat + 256, 512, Wc1 + 256, 768, 256, nullptr, nullptr, Q21, 256, 0, 0, 0);
    gemm_bt<0,false><<<dim3(2,  64), 256, 0, stream>>>(A3cat + 512, 768, Wc1 + 512, 768, 256, nullptr, nullptr, Q31, 256, 0, 0, 0);
    gemm_bt<0,false><<<dim3(2,  64), 256, 0, stream>>>(A3cat + 512, 768, Wc2 + 512, 768, 256, nullptr, nullptr, Q32, 256, 0, 0, 0);
    // 4. main fusion GEMMs (+bias)
    gemm_bt<0,true><<<dim3(2,1024), 256, 0, stream>>>(xn1,   256, Wc1, 768, 256, c1b, nullptr, Q11, 256, 0, 0, 0);
    gemm_bt<0,true><<<dim3(2, 256), 256, 0, stream>>>(A2cat, 512, Wc2, 768, 512, c2b, nullptr, s2,  256, 0, 0, 0);
    gemm_bt<0,true><<<dim3(2,  64), 256, 0, stream>>>(A3cat, 768, Wc3, 768, 768, c3b, nullptr, s3,  256, 0, 0, 0);
    // 5. vectorized resample-adds
    fuse1v<<<16384, 256, 0, stream>>>(Q11, Q21, Q31, s1);
    fuse2v<<< 4096, 256, 0, stream>>>(s2, Q32);
    // 6. QKV GEMMs (bias) -> qkv (reuses R1)
    gemm_bt<0,true><<<dim3(6,1024), 256, 0, stream>>>(s1, 256, Wq1, 256, 256, q1b, nullptr, kv1, 768, 0, 0, 0);
    gemm_bt<0,true><<<dim3(6, 256), 256, 0, stream>>>(s2, 256, Wq2, 256, 256, q2b, nullptr, kv2, 768, 0, 0, 0);
    gemm_bt<0,true><<<dim3(6,  64), 256, 0, stream>>>(s3, 256, Wq3, 256, 256, q3b, nullptr, kv3, 768, 0, 0, 0);
    // 7. windowed attention (writes over s region)
    attn_kernel<<<16384, 256, 0, stream>>>(kv1, at1, rpb1, 64, 16, 256, 4096, 65536);
    attn_kernel<<< 4096, 256, 0, stream>>>(kv2, at2, rpb2, 32,  8,  64, 1024, 16384);
    attn_kernel<<< 1024, 256, 0, stream>>>(kv3, at3, rpb3, 16,  4,  16,  256,  4096);
    // 8. proj GEMMs + residual -> d_out (f32, token-remapped rows)
    gemm_bt<1,true><<<dim3(2,1024), 256, 0, stream>>>(at1, 256, Wp1, 256, 256, p1b, x, out, 256, 4096, 5376, 0);
    gemm_bt<1,true><<<dim3(2, 256), 256, 0, stream>>>(at2, 256, Wp2, 256, 256, p2b, x, out, 256, 1024, 5376, 4096);
    gemm_bt<1,true><<<dim3(2,  64), 256, 0, stream>>>(at3, 256, Wp3, 256, 256, p3b, x, out, 256,  256, 5376, 5120);
    // 9. LN2 on d_out -> ln2 (reuses R1)
    ln_kernel<false><<<MT/4, 256, 0, stream>>>(out, n3g, n3b, ln2, nullptr, nullptr, MT);
    // 10. FFN GEMM, accumulate into d_out
    gemm_bt<2,true><<<dim3(2, MT/128), 256, 0, stream>>>(ln2, 256, Wff, 256, 256, ffb, nullptr, out, 256, MT, 0, 0);
}